// Round 2
// baseline (99.842 us; speedup 1.0000x reference)
//
#include <hip/hip_runtime.h>

#define HH 512
#define DD 64
#define MROWS 64
#define TPB 512            // 8 waves: each owns 64 rows x 64 cols (4rt x 4ct)
#define NBLK (8192 / MROWS)
#define LP 520             // u16 pitch for 64x512 LDS tiles

typedef unsigned short u16;
typedef unsigned int u32;
typedef short s16x8 __attribute__((ext_vector_type(8)));   // 8 bf16 = 4 VGPRs
typedef float f32x4 __attribute__((ext_vector_type(4)));

#define MFMA16(A,B,C) __builtin_amdgcn_mfma_f32_16x16x32_bf16((A),(B),(C),0,0,0)

// ---- workspace layout (u16 element offsets), fragment-linear:
//   addr = ntile*16*K + ks*512 + lane*8 ; value[j] = M[k = ks*32+(lane>>4)*8+j][n = nt*16+(lane&15)]
#define OFF_EF   0
#define OFF_W2F  (HH*HH)
#define OFF_W1F  (2*HH*HH)
#define OFF_W3F  (2*HH*HH + HH*DD)
#define OFF_Z0B  ((2*HH*HH + 2*HH*DD)*2)   // byte offset of z0 (f32[512])

__device__ __forceinline__ u16 f2bf(float f) {
    unsigned u = __builtin_bit_cast(unsigned, f);
    u += 0x7fffu + ((u >> 16) & 1u);
    return (u16)(u >> 16);
}
__device__ __forceinline__ float bf2f(u16 h) {
    return __builtin_bit_cast(float, (unsigned)h << 16);
}
__device__ __forceinline__ float fast_tanh(float x) {
    float e = __expf(2.0f * x);
    return 1.0f - 2.0f * __builtin_amdgcn_rcpf(e + 1.0f);
}

// =======================================================================
// precompute: 137 blocks x 256 threads (unchanged — ~4 us)
// =======================================================================
__global__ __launch_bounds__(256) void precompute(
    const float* __restrict__ t,  const float* __restrict__ W1,
    const float* __restrict__ b1, const float* __restrict__ W2,
    const float* __restrict__ W3, u16* __restrict__ ws16, float* __restrict__ z0)
{
    __shared__ float T[16 * 264 > 256 * 20 ? 16 * 264 : 256 * 20];
    u16* Ef  = ws16 + OFF_EF;
    u16* W2f = ws16 + OFF_W2F;
    u16* W1f = ws16 + OFF_W1F;
    u16* W3f = ws16 + OFF_W3F;

    const int bid = blockIdx.x, tid = threadIdx.x;
    const int lane = tid & 63, wv = tid >> 6;
    const int m16 = lane & 15, q = lane >> 4;

    if (bid < 64) {
        const int nt = bid >> 1, bh = bid & 1;
        const int a0 = nt * 16, b0 = bh * 256;
        s16x8 afh[2], afl[2];
#pragma unroll
        for (int h = 0; h < 2; ++h)
#pragma unroll
            for (int j = 0; j < 8; ++j) {
                int i = h * 32 + q * 8 + j;
                float v = W1[(1 + i) * HH + a0 + m16];
                u16 hi = f2bf(v);
                afh[h][j] = (short)hi;
                afl[h][j] = (short)f2bf(v - bf2f(hi));
            }
#pragma unroll
        for (int bt = 0; bt < 4; ++bt) {
            int bl = wv * 64 + bt * 16;
            s16x8 bfh[2], bfl[2];
#pragma unroll
            for (int h = 0; h < 2; ++h) {
                const float* src = W3 + (b0 + bl + m16) * DD + h * 32 + q * 8;
                float4 p0 = *(const float4*)(src);
                float4 p1 = *(const float4*)(src + 4);
                float vv[8] = {p0.x,p0.y,p0.z,p0.w,p1.x,p1.y,p1.z,p1.w};
#pragma unroll
                for (int j = 0; j < 8; ++j) {
                    u16 hi = f2bf(vv[j]);
                    bfh[h][j] = (short)hi;
                    bfl[h][j] = (short)f2bf(vv[j] - bf2f(hi));
                }
            }
            f32x4 c = {0.f, 0.f, 0.f, 0.f};
#pragma unroll
            for (int h = 0; h < 2; ++h) {
                c = MFMA16(afh[h], bfh[h], c);
                c = MFMA16(afh[h], bfl[h], c);
                c = MFMA16(afl[h], bfh[h], c);
            }
#pragma unroll
            for (int r = 0; r < 4; ++r)
                T[(4 * q + r) * 264 + bl + m16] = c[r];
        }
        __syncthreads();
#pragma unroll
        for (int p = 0; p < 2; ++p) {
            int ksl = p * 4 + wv;
            int al  = m16;
            int blc = ksl * 32 + q * 8;
            const float* w2p = W2 + (a0 + al) * HH + b0 + blc;
            float4 wa = *(const float4*)(w2p), wb = *(const float4*)(w2p + 4);
            const float* glp = T + al * 264 + blc;
            s16x8 o;
            o[0]=(short)f2bf(wa.x*glp[0]); o[1]=(short)f2bf(wa.y*glp[1]);
            o[2]=(short)f2bf(wa.z*glp[2]); o[3]=(short)f2bf(wa.w*glp[3]);
            o[4]=(short)f2bf(wb.x*glp[4]); o[5]=(short)f2bf(wb.y*glp[5]);
            o[6]=(short)f2bf(wb.z*glp[6]); o[7]=(short)f2bf(wb.w*glp[7]);
            *(s16x8*)(Ef + nt * 8192 + (b0 / 32 + ksl) * 512 + lane * 8) = o;
        }
        if (bh == 0 && tid < 128) {
            int ks = tid >> 6, ln = tid & 63;
            int n  = nt * 16 + (ln & 15);
            int k0 = ks * 32 + (ln >> 4) * 8;
            s16x8 o;
#pragma unroll
            for (int j = 0; j < 8; ++j) o[j] = (short)f2bf(W1[(1 + k0 + j) * HH + n]);
            *(s16x8*)(W1f + nt * 1024 + ks * 512 + ln * 8) = o;
        }
    } else if (bid < 128) {
        const int nt = (bid - 64) >> 1, kh = (bid - 64) & 1;
        const int n0 = nt * 16, k0 = kh * 256;
#pragma unroll
        for (int it = 0; it < 4; ++it) {
            int r = (tid >> 2) + it * 64;
            int c = (tid & 3) * 4;
            float4 v = *(const float4*)(W2 + (k0 + r) * HH + n0 + c);
            *(float4*)(T + r * 20 + c) = v;
        }
        __syncthreads();
#pragma unroll
        for (int p = 0; p < 2; ++p) {
            int ksl = p * 4 + wv;
            int kq  = ksl * 32 + q * 8;
            s16x8 o;
#pragma unroll
            for (int j = 0; j < 8; ++j) o[j] = (short)f2bf(T[(kq + j) * 20 + m16]);
            *(s16x8*)(W2f + nt * 8192 + (k0 / 32 + ksl) * 512 + lane * 8) = o;
        }
    } else if (bid < 136) {
        const int ot = (bid - 128) >> 1, kh = (bid - 128) & 1;
        const int o0 = ot * 16, k0 = kh * 256;
#pragma unroll
        for (int it = 0; it < 4; ++it) {
            int r = (tid >> 2) + it * 64;
            int c = (tid & 3) * 4;
            float4 v = *(const float4*)(W3 + (k0 + r) * DD + o0 + c);
            *(float4*)(T + r * 20 + c) = v;
        }
        __syncthreads();
#pragma unroll
        for (int p = 0; p < 2; ++p) {
            int ksl = p * 4 + wv;
            int kq  = ksl * 32 + q * 8;
            s16x8 o;
#pragma unroll
            for (int j = 0; j < 8; ++j) o[j] = (short)f2bf(T[(kq + j) * 20 + m16]);
            *(s16x8*)(W3f + ot * 8192 + (k0 / 32 + ksl) * 512 + lane * 8) = o;
        }
    } else {
        for (int n = tid; n < HH; n += 256)
            z0[n] = b1[n] + t[0] * W1[n];
    }
}

// =======================================================================
// cnf_main: 128 blocks x 512 threads (8 waves), MROWS=64.
// Halves total B-operand L2 traffic (each block reads the full 1.15MB
// fragment ws once but now covers 64 rows). Each wave owns 64x64 output
// (4rt x 4ct). h1s/h2s aliased in LDS (extra barrier after phase-2 reads);
// xs aliases d2s as before. B/E prefetch depth 3, A double-buffered.
// =======================================================================
__global__ __launch_bounds__(TPB, 2) void cnf_main(
    const float* __restrict__ x,  const u16* __restrict__ ws16,
    const float* __restrict__ z0, const float* __restrict__ b2,
    const float* __restrict__ b3, float* __restrict__ out)
{
    __shared__ u16 h12s[MROWS * LP];    // h1, then (after barrier) h2
    __shared__ u16 d2s[MROWS * LP];     // xs before phase 2, then d2
    __shared__ float z0s[HH];
    __shared__ float b2s[HH];
    __shared__ float b3s[DD];
    __shared__ float divacc[8][MROWS];

    const u16* Ef  = ws16 + OFF_EF;
    const u16* W2f = ws16 + OFF_W2F;
    const u16* W1f = ws16 + OFF_W1F;
    const u16* W3f = ws16 + OFF_W3F;

    const int tid  = threadIdx.x;
    const int lane = tid & 63;
    const int w    = tid >> 6;        // 8 waves
    const int m16  = lane & 15;
    const int q    = lane >> 4;
    const int kq   = q * 8;
    const int r0   = blockIdx.x * MROWS;

    // decorrelation keys: co-XCD blocks (stride 8 under round-robin) differ
    const int noff = (blockIdx.x >> 3) & 31;
    const int koff = (blockIdx.x >> 3) & 15;

    // wave's four n-tiles (a permutation of 0..31 across (w,ct))
    int tile[4];
#pragma unroll
    for (int ct = 0; ct < 4; ++ct) tile[ct] = (4 * w + ct + noff) & 31;

    u16* xs = d2s;                    // overlap: xs dead after phase 1

    // ---- top-of-kernel global prefetch: W1f frags + W2f depth-3 ----
    s16x8 p1b[4][2];
#pragma unroll
    for (int ct = 0; ct < 4; ++ct) {
        const u16* bb = W1f + tile[ct] * 1024 + lane * 8;
        p1b[ct][0] = *(const s16x8*)(bb);
        p1b[ct][1] = *(const s16x8*)(bb + 512);
    }
    const u16* w2bp[4];
#pragma unroll
    for (int ct = 0; ct < 4; ++ct) w2bp[ct] = W2f + tile[ct] * 8192 + lane * 8;
    s16x8 Bv[3][4];                   // [slot][ct], rolling depth-3
#pragma unroll
    for (int k = 0; k < 3; ++k) {
        const int kk = (koff + k) & 15;
#pragma unroll
        for (int ct = 0; ct < 4; ++ct)
            Bv[k][ct] = *(const s16x8*)(w2bp[ct] + kk * 512);
    }

    // ---- stage ----
    for (int idx = tid; idx < MROWS * DD; idx += TPB) {
        int r = idx >> 6, c = idx & 63;
        xs[r * 72 + c] = f2bf(x[(r0 + r) * (DD + 1) + c]);
    }
    z0s[tid] = z0[tid];               // TPB == HH
    b2s[tid] = b2[tid];
    if (tid < DD) b3s[tid] = b3[tid];
    __syncthreads();

    float d1reg[4][4][4];             // d1 = 1-h1^2, kept in regs for phase 4

    // ---- phase 1: h1 = tanh([t,x]@W1 + z0), K=64 ----
    {
        s16x8 xa[4][2];
#pragma unroll
        for (int rt = 0; rt < 4; ++rt)
#pragma unroll
            for (int h = 0; h < 2; ++h)
                xa[rt][h] = *(const s16x8*)(xs + (rt * 16 + m16) * 72 + h * 32 + kq);
#pragma unroll
        for (int ct = 0; ct < 4; ++ct) {
            const int col = tile[ct] * 16 + m16;
            const float zc = z0s[col];
#pragma unroll
            for (int rt = 0; rt < 4; ++rt) {
                f32x4 c = {0.f, 0.f, 0.f, 0.f};
                c = MFMA16(xa[rt][0], p1b[ct][0], c);
                c = MFMA16(xa[rt][1], p1b[ct][1], c);
#pragma unroll
                for (int i = 0; i < 4; ++i) {
                    float hv = fast_tanh(c[i] + zc);
                    h12s[(rt * 16 + 4 * q + i) * LP + col] = f2bf(hv);
                    d1reg[rt][ct][i] = 1.0f - hv * hv;
                }
            }
        }
    }
    __syncthreads();

    // ---- phase 2: h2 = tanh(h1@W2 + b2); A double-buffered, B depth-3 ----
    f32x4 acc[4][4];
#pragma unroll
    for (int rt = 0; rt < 4; ++rt)
#pragma unroll
        for (int ct = 0; ct < 4; ++ct) acc[rt][ct] = (f32x4){0.f,0.f,0.f,0.f};
    {
        const u16* ap[4];
#pragma unroll
        for (int rt = 0; rt < 4; ++rt) ap[rt] = h12s + (rt * 16 + m16) * LP + kq;
        s16x8 Aq[2][4];               // [parity][rt]
        {
            const int kk0 = koff & 15;
#pragma unroll
            for (int rt = 0; rt < 4; ++rt)
                Aq[0][rt] = *(const s16x8*)(ap[rt] + kk0 * 32);
        }
#pragma unroll
        for (int ks = 0; ks < 16; ++ks) {
            const int sl = ks % 3, cur = ks & 1;
            if (ks < 15) {
                const int kn = (koff + ks + 1) & 15;
#pragma unroll
                for (int rt = 0; rt < 4; ++rt)
                    Aq[cur ^ 1][rt] = *(const s16x8*)(ap[rt] + kn * 32);
            }
#pragma unroll
            for (int ct = 0; ct < 4; ++ct)
#pragma unroll
                for (int rt = 0; rt < 4; ++rt)
                    acc[rt][ct] = MFMA16(Aq[cur][rt], Bv[sl][ct], acc[rt][ct]);
            if (ks < 13) {
                const int kn = (koff + ks + 3) & 15;
#pragma unroll
                for (int ct = 0; ct < 4; ++ct)
                    Bv[sl][ct] = *(const s16x8*)(w2bp[ct] + kn * 512);
            }
        }
    }

    // ---- issue phase-4 Ef preloads (slots 0,1) before the h1-read barrier ----
    const u16* efp[4];
#pragma unroll
    for (int ct = 0; ct < 4; ++ct) efp[ct] = Ef + tile[ct] * 8192 + lane * 8;
    s16x8 Ev[3][4];                   // [slot][ct], rolling depth-3
#pragma unroll
    for (int k = 0; k < 2; ++k) {
        const int kk = (koff + k) & 15;
#pragma unroll
        for (int ct = 0; ct < 4; ++ct)
            Ev[k][ct] = *(const s16x8*)(efp[ct] + kk * 512);
    }

    // all waves done READING h1s before we overwrite it with h2
    __syncthreads();

    // ---- phase-2 epilogue: tanh -> h2 (into h12s), d2 -> d2s ----
#pragma unroll
    for (int rt = 0; rt < 4; ++rt)
#pragma unroll
        for (int ct = 0; ct < 4; ++ct) {
            const int col = tile[ct] * 16 + m16;
            const float bc = b2s[col];
#pragma unroll
            for (int i = 0; i < 4; ++i) {
                int row = rt * 16 + 4 * q + i;
                float hv = fast_tanh(acc[rt][ct][i] + bc);
                h12s[row * LP + col] = f2bf(hv);
                d2s[row * LP + col] = f2bf(1.0f - hv * hv);
            }
        }
    __syncthreads();

    // ---- phase 3 (all 8 waves, two 16x16 tiles each, shared A): dx = h2@W3 + b3 ----
    {
        const int rowt = w >> 1;
        const int ot0  = (((2 * w    ) & 3) + noff) & 3;
        const int ot1  = (((2 * w + 1) & 3) + noff) & 3;
        const u16* ap3 = h12s + (rowt * 16 + m16) * LP + kq;
        const u16* bp0 = W3f + ot0 * 8192 + lane * 8;
        const u16* bp1 = W3f + ot1 * 8192 + lane * 8;
        s16x8 R0[4], R1[4];
#pragma unroll
        for (int k = 0; k < 4; ++k) {
            const int kk = (koff + k) & 15;
            R0[k] = *(const s16x8*)(bp0 + kk * 512);
            R1[k] = *(const s16x8*)(bp1 + kk * 512);
        }
        f32x4 c0 = {0.f,0.f,0.f,0.f}, c1 = {0.f,0.f,0.f,0.f};
#pragma unroll
        for (int ks = 0; ks < 16; ++ks) {
            const int kk = (koff + ks) & 15;
            s16x8 f = *(const s16x8*)(ap3 + kk * 32);
            const int sl = ks & 3;
            c0 = MFMA16(f, R0[sl], c0);
            c1 = MFMA16(f, R1[sl], c1);
            if (ks < 12) {
                const int kn = (koff + ks + 4) & 15;
                R0[sl] = *(const s16x8*)(bp0 + kn * 512);
                R1[sl] = *(const s16x8*)(bp1 + kn * 512);
            }
        }
        const int o0c = ot0 * 16 + m16;
        const int o1c = ot1 * 16 + m16;
#pragma unroll
        for (int i = 0; i < 4; ++i) {
            const int row = r0 + rowt * 16 + 4 * q + i;
            out[row * (DD + 1) + o0c] = c0[i] + b3s[o0c];
            out[row * (DD + 1) + o1c] = c1[i] + b3s[o1c];
        }
    }

    // ---- phase 4 (all 8 waves): M = d2@Ef; div = sum d1 .* M ----
    {
        f32x4 g[4][4];
#pragma unroll
        for (int rt = 0; rt < 4; ++rt)
#pragma unroll
            for (int ct = 0; ct < 4; ++ct) g[rt][ct] = (f32x4){0.f,0.f,0.f,0.f};

        // fill Ef slot 2
        {
            const int kk = (koff + 2) & 15;
#pragma unroll
            for (int ct = 0; ct < 4; ++ct)
                Ev[2][ct] = *(const s16x8*)(efp[ct] + kk * 512);
        }
        const u16* dp[4];
#pragma unroll
        for (int rt = 0; rt < 4; ++rt) dp[rt] = d2s + (rt * 16 + m16) * LP + kq;
        s16x8 Aq[2][4];
        {
            const int kk0 = koff & 15;
#pragma unroll
            for (int rt = 0; rt < 4; ++rt)
                Aq[0][rt] = *(const s16x8*)(dp[rt] + kk0 * 32);
        }
#pragma unroll
        for (int ks = 0; ks < 16; ++ks) {
            const int sl = ks % 3, cur = ks & 1;
            if (ks < 15) {
                const int kn = (koff + ks + 1) & 15;
#pragma unroll
                for (int rt = 0; rt < 4; ++rt)
                    Aq[cur ^ 1][rt] = *(const s16x8*)(dp[rt] + kn * 32);
            }
#pragma unroll
            for (int ct = 0; ct < 4; ++ct)
#pragma unroll
                for (int rt = 0; rt < 4; ++rt)
                    g[rt][ct] = MFMA16(Aq[cur][rt], Ev[sl][ct], g[rt][ct]);
            if (ks < 13) {
                const int kn = (koff + ks + 3) & 15;
#pragma unroll
                for (int ct = 0; ct < 4; ++ct)
                    Ev[sl][ct] = *(const s16x8*)(efp[ct] + kn * 512);
            }
        }
#pragma unroll
        for (int rt = 0; rt < 4; ++rt)
#pragma unroll
            for (int i = 0; i < 4; ++i) {
                float v = d1reg[rt][0][i] * g[rt][0][i]
                        + d1reg[rt][1][i] * g[rt][1][i]
                        + d1reg[rt][2][i] * g[rt][2][i]
                        + d1reg[rt][3][i] * g[rt][3][i];
                v += __shfl_xor(v, 1, 64);
                v += __shfl_xor(v, 2, 64);
                v += __shfl_xor(v, 4, 64);
                v += __shfl_xor(v, 8, 64);
                if (m16 == 0) divacc[w][rt * 16 + 4 * q + i] = v;
            }
    }
    __syncthreads();

    if (tid < MROWS) {
        float s = 0.0f;
#pragma unroll
        for (int ww = 0; ww < 8; ++ww) s += divacc[ww][tid];
        out[(r0 + tid) * (DD + 1) + DD] = s;
    }
}

extern "C" void kernel_launch(void* const* d_in, const int* in_sizes, int n_in,
                              void* d_out, int out_size, void* d_ws, size_t ws_size,
                              hipStream_t stream) {
    const float* t  = (const float*)d_in[0];
    const float* x  = (const float*)d_in[1];
    const float* W1 = (const float*)d_in[2];
    const float* b1 = (const float*)d_in[3];
    const float* W2 = (const float*)d_in[4];
    const float* b2 = (const float*)d_in[5];
    const float* W3 = (const float*)d_in[6];
    const float* b3 = (const float*)d_in[7];
    float* out = (float*)d_out;

    u16*   ws16 = (u16*)d_ws;
    float* z0   = (float*)((char*)d_ws + OFF_Z0B);

    precompute<<<137, 256, 0, stream>>>(t, W1, b1, W2, W3, ws16, z0);
    cnf_main<<<NBLK, TPB, 0, stream>>>(x, ws16, z0, b2, b3, out);
}

// Round 3
// 93.425 us; speedup vs baseline: 1.0687x; 1.0687x over previous
//
#include <hip/hip_runtime.h>

#define HH 512
#define DD 64
#define MROWS 32
#define TPB 512            // 8 waves: rows shared, each wave owns 4 n-tiles
#define LP 520             // u16 pitch for 32x512 LDS tiles

typedef unsigned short u16;
typedef short s16x8 __attribute__((ext_vector_type(8)));   // 8 bf16 = 4 VGPRs
typedef float f32x4 __attribute__((ext_vector_type(4)));

#define MFMA16(A,B,C) __builtin_amdgcn_mfma_f32_16x16x32_bf16((A),(B),(C),0,0,0)

// ---- workspace layout (u16 element offsets), fragment-linear:
//   addr = ntile*16*K + ks*512 + lane*8 ; value[j] = M[k = ks*32+(lane>>4)*8+j][n = nt*16+(lane&15)]
#define OFF_EF   0
#define OFF_W2F  (HH*HH)
#define OFF_W1F  (2*HH*HH)
#define OFF_W3F  (2*HH*HH + HH*DD)
#define OFF_Z0B  ((2*HH*HH + 2*HH*DD)*2)   // byte offset of z0 (f32[512])

__device__ __forceinline__ u16 f2bf(float f) {
    unsigned u = __builtin_bit_cast(unsigned, f);
    u += 0x7fffu + ((u >> 16) & 1u);
    return (u16)(u >> 16);
}
__device__ __forceinline__ float bf2f(u16 h) {
    return __builtin_bit_cast(float, (unsigned)h << 16);
}
__device__ __forceinline__ float fast_tanh(float x) {
    float e = __expf(2.0f * x);
    return 1.0f - 2.0f * __builtin_amdgcn_rcpf(e + 1.0f);
}

// counted waits: vmcnt(N) == allow N newest vm-ops outstanding (in-order retire)
template<int N> __device__ __forceinline__ void wait_vmcnt() {
    asm volatile("s_waitcnt vmcnt(%0)" :: "n"(N) : "memory");
}
__device__ __forceinline__ void wait_lgkm0() {
    asm volatile("s_waitcnt lgkmcnt(0)" ::: "memory");
}
// async global->LDS DMA, 16B/lane; LDS dest = wave-uniform base + lane*16
__device__ __forceinline__ void dma16(const u16* g, u16* l) {
    __builtin_amdgcn_global_load_lds(
        (const __attribute__((address_space(1))) void*)g,
        (__attribute__((address_space(3))) void*)l, 16, 0, 0);
}
// one k-chunk for this wave: 4 consecutive n-tiles' fragments at k-step kk
__device__ __forceinline__ void issue4(const u16* base, int kk, u16* dst) {
#pragma unroll
    for (int ct = 0; ct < 4; ++ct)
        dma16(base + ct * 8192 + kk * 512, dst + ct * 512);
}

// =======================================================================
// precompute: 137 blocks x 256 threads (unchanged — ~4 us)
// =======================================================================
__global__ __launch_bounds__(256) void precompute(
    const float* __restrict__ t,  const float* __restrict__ W1,
    const float* __restrict__ b1, const float* __restrict__ W2,
    const float* __restrict__ W3, u16* __restrict__ ws16, float* __restrict__ z0)
{
    __shared__ float T[16 * 264 > 256 * 20 ? 16 * 264 : 256 * 20];
    u16* Ef  = ws16 + OFF_EF;
    u16* W2f = ws16 + OFF_W2F;
    u16* W1f = ws16 + OFF_W1F;
    u16* W3f = ws16 + OFF_W3F;

    const int bid = blockIdx.x, tid = threadIdx.x;
    const int lane = tid & 63, wv = tid >> 6;
    const int m16 = lane & 15, q = lane >> 4;

    if (bid < 64) {
        const int nt = bid >> 1, bh = bid & 1;
        const int a0 = nt * 16, b0 = bh * 256;
        s16x8 afh[2], afl[2];
#pragma unroll
        for (int h = 0; h < 2; ++h)
#pragma unroll
            for (int j = 0; j < 8; ++j) {
                int i = h * 32 + q * 8 + j;
                float v = W1[(1 + i) * HH + a0 + m16];
                u16 hi = f2bf(v);
                afh[h][j] = (short)hi;
                afl[h][j] = (short)f2bf(v - bf2f(hi));
            }
#pragma unroll
        for (int bt = 0; bt < 4; ++bt) {
            int bl = wv * 64 + bt * 16;
            s16x8 bfh[2], bfl[2];
#pragma unroll
            for (int h = 0; h < 2; ++h) {
                const float* src = W3 + (b0 + bl + m16) * DD + h * 32 + q * 8;
                float4 p0 = *(const float4*)(src);
                float4 p1 = *(const float4*)(src + 4);
                float vv[8] = {p0.x,p0.y,p0.z,p0.w,p1.x,p1.y,p1.z,p1.w};
#pragma unroll
                for (int j = 0; j < 8; ++j) {
                    u16 hi = f2bf(vv[j]);
                    bfh[h][j] = (short)hi;
                    bfl[h][j] = (short)f2bf(vv[j] - bf2f(hi));
                }
            }
            f32x4 c = {0.f, 0.f, 0.f, 0.f};
#pragma unroll
            for (int h = 0; h < 2; ++h) {
                c = MFMA16(afh[h], bfh[h], c);
                c = MFMA16(afh[h], bfl[h], c);
                c = MFMA16(afl[h], bfh[h], c);
            }
#pragma unroll
            for (int r = 0; r < 4; ++r)
                T[(4 * q + r) * 264 + bl + m16] = c[r];
        }
        __syncthreads();
#pragma unroll
        for (int p = 0; p < 2; ++p) {
            int ksl = p * 4 + wv;
            int al  = m16;
            int blc = ksl * 32 + q * 8;
            const float* w2p = W2 + (a0 + al) * HH + b0 + blc;
            float4 wa = *(const float4*)(w2p), wb = *(const float4*)(w2p + 4);
            const float* glp = T + al * 264 + blc;
            s16x8 o;
            o[0]=(short)f2bf(wa.x*glp[0]); o[1]=(short)f2bf(wa.y*glp[1]);
            o[2]=(short)f2bf(wa.z*glp[2]); o[3]=(short)f2bf(wa.w*glp[3]);
            o[4]=(short)f2bf(wb.x*glp[4]); o[5]=(short)f2bf(wb.y*glp[5]);
            o[6]=(short)f2bf(wb.z*glp[6]); o[7]=(short)f2bf(wb.w*glp[7]);
            *(s16x8*)(Ef + nt * 8192 + (b0 / 32 + ksl) * 512 + lane * 8) = o;
        }
        if (bh == 0 && tid < 128) {
            int ks = tid >> 6, ln = tid & 63;
            int n  = nt * 16 + (ln & 15);
            int k0 = ks * 32 + (ln >> 4) * 8;
            s16x8 o;
#pragma unroll
            for (int j = 0; j < 8; ++j) o[j] = (short)f2bf(W1[(1 + k0 + j) * HH + n]);
            *(s16x8*)(W1f + nt * 1024 + ks * 512 + ln * 8) = o;
        }
    } else if (bid < 128) {
        const int nt = (bid - 64) >> 1, kh = (bid - 64) & 1;
        const int n0 = nt * 16, k0 = kh * 256;
#pragma unroll
        for (int it = 0; it < 4; ++it) {
            int r = (tid >> 2) + it * 64;
            int c = (tid & 3) * 4;
            float4 v = *(const float4*)(W2 + (k0 + r) * HH + n0 + c);
            *(float4*)(T + r * 20 + c) = v;
        }
        __syncthreads();
#pragma unroll
        for (int p = 0; p < 2; ++p) {
            int ksl = p * 4 + wv;
            int kq  = ksl * 32 + q * 8;
            s16x8 o;
#pragma unroll
            for (int j = 0; j < 8; ++j) o[j] = (short)f2bf(T[(kq + j) * 20 + m16]);
            *(s16x8*)(W2f + nt * 8192 + (k0 / 32 + ksl) * 512 + lane * 8) = o;
        }
    } else if (bid < 136) {
        const int ot = (bid - 128) >> 1, kh = (bid - 128) & 1;
        const int o0 = ot * 16, k0 = kh * 256;
#pragma unroll
        for (int it = 0; it < 4; ++it) {
            int r = (tid >> 2) + it * 64;
            int c = (tid & 3) * 4;
            float4 v = *(const float4*)(W3 + (k0 + r) * DD + o0 + c);
            *(float4*)(T + r * 20 + c) = v;
        }
        __syncthreads();
#pragma unroll
        for (int p = 0; p < 2; ++p) {
            int ksl = p * 4 + wv;
            int kq  = ksl * 32 + q * 8;
            s16x8 o;
#pragma unroll
            for (int j = 0; j < 8; ++j) o[j] = (short)f2bf(T[(kq + j) * 20 + m16]);
            *(s16x8*)(W3f + ot * 8192 + (k0 / 32 + ksl) * 512 + lane * 8) = o;
        }
    } else {
        for (int n = tid; n < HH; n += 256)
            z0[n] = b1[n] + t[0] * W1[n];
    }
}

// =======================================================================
// cnf_main: 256 blocks x 512 threads (8 waves), MROWS=32.
// B-fragment streams (W2f phase 2, Ef phase 4) staged via async
// global_load_lds into a per-wave 2-slot LDS ring with counted vmcnt(4)
// waits: >=32KB in flight per CU (vs ~2KB with register prefetch) turns
// the latency-bound stream (~10 B/cyc/CU observed) into a BW-bound one.
// h1/h2 aliased in LDS (extra barrier); d2s kept (bit-identical numerics);
// W3 frags preloaded into 64 VGPRs so phase-4 vmcnt counting stays clean.
// =======================================================================
__global__ __launch_bounds__(TPB, 2) void cnf_main(
    const float* __restrict__ x,  const u16* __restrict__ ws16,
    const float* __restrict__ z0, const float* __restrict__ b2,
    const float* __restrict__ b3, float* __restrict__ out)
{
    __shared__ u16 h12s[MROWS * LP];     // h1, then (after barrier) h2
    __shared__ u16 d2s[MROWS * LP];      // xs before phase 2, then d2
    __shared__ u16 Bst[8][2][2048];      // per-wave 2-slot DMA ring (4KB/slot)
    __shared__ float z0s[HH];
    __shared__ float b2s[HH];
    __shared__ float b3s[DD];
    __shared__ float divacc[8][MROWS];

    const u16* Ef  = ws16 + OFF_EF;
    const u16* W2f = ws16 + OFF_W2F;
    const u16* W1f = ws16 + OFF_W1F;
    const u16* W3f = ws16 + OFF_W3F;

    const int tid  = threadIdx.x;
    const int lane = tid & 63;
    const int w    = tid >> 6;        // 8 waves
    const int m16  = lane & 15;
    const int q    = lane >> 4;
    const int kq   = q * 8;
    const int r0   = blockIdx.x * MROWS;

    // k-order rotation decorrelates co-XCD blocks' L2 access
    const int koff = (blockIdx.x >> 3) & 15;

    u16* xs = d2s;                    // overlap: xs dead after phase 1

    const u16* w2b = W2f + (4 * w) * 8192 + lane * 8;  // wave's 4 tiles, contiguous
    const u16* efb = Ef  + (4 * w) * 8192 + lane * 8;
    u16* st0 = &Bst[w][0][0];
    u16* st1 = &Bst[w][1][0];

    // ---- W1f register prefetch (phase-1 B operands) ----
    s16x8 p1b[4][2];
#pragma unroll
    for (int ct = 0; ct < 4; ++ct) {
        const u16* bb = W1f + (4 * w + ct) * 1024 + lane * 8;
        p1b[ct][0] = *(const s16x8*)(bb);
        p1b[ct][1] = *(const s16x8*)(bb + 512);
    }

    // ---- stage ----
    for (int idx = tid; idx < MROWS * DD; idx += TPB) {
        int r = idx >> 6, c = idx & 63;
        xs[r * 72 + c] = f2bf(x[(r0 + r) * (DD + 1) + c]);
    }
    z0s[tid] = z0[tid];               // TPB == HH
    b2s[tid] = b2[tid];
    if (tid < DD) b3s[tid] = b3[tid];
    __syncthreads();

    float d1reg[2][4][4];             // d1 = 1-h1^2, kept in regs for phase 4

    // ---- phase 1: h1 = tanh([t,x]@W1 + z0), K=64 ----
    {
        s16x8 xa[2][2];
#pragma unroll
        for (int rt = 0; rt < 2; ++rt)
#pragma unroll
            for (int h = 0; h < 2; ++h)
                xa[rt][h] = *(const s16x8*)(xs + (rt * 16 + m16) * 72 + h * 32 + kq);
#pragma unroll
        for (int ct = 0; ct < 4; ++ct) {
            const int col = (4 * w + ct) * 16 + m16;
            const float zc = z0s[col];
#pragma unroll
            for (int rt = 0; rt < 2; ++rt) {
                f32x4 c = {0.f, 0.f, 0.f, 0.f};
                c = MFMA16(xa[rt][0], p1b[ct][0], c);
                c = MFMA16(xa[rt][1], p1b[ct][1], c);
#pragma unroll
                for (int i = 0; i < 4; ++i) {
                    float hv = fast_tanh(c[i] + zc);
                    h12s[(rt * 16 + 4 * q + i) * LP + col] = f2bf(hv);
                    d1reg[rt][ct][i] = 1.0f - hv * hv;
                }
            }
        }
    }

    // ---- W2f DMA prologue (slots 0,1) ----
    issue4(w2b, (koff + 0) & 15, st0);
    issue4(w2b, (koff + 1) & 15, st1);
    __syncthreads();                  // h1 visible (barrier also drains vmcnt)

    // ---- phase 2: h2 = tanh(h1@W2 + b2); DMA-staged B, 2-slot ring ----
    f32x4 acc[2][4];
#pragma unroll
    for (int rt = 0; rt < 2; ++rt)
#pragma unroll
        for (int ct = 0; ct < 4; ++ct) acc[rt][ct] = (f32x4){0.f,0.f,0.f,0.f};
    {
        const u16* ap0 = h12s + m16 * LP + kq;
        const u16* ap1 = h12s + (16 + m16) * LP + kq;
#pragma unroll
        for (int ks = 0; ks < 16; ++ks) {
            if (ks < 15) wait_vmcnt<4>(); else wait_vmcnt<0>();
            u16* sb = (ks & 1) ? st1 : st0;
            const u16* bb = sb + lane * 8;
            s16x8 b0v = *(const s16x8*)(bb);
            s16x8 b1v = *(const s16x8*)(bb + 512);
            s16x8 b2v = *(const s16x8*)(bb + 1024);
            s16x8 b3v = *(const s16x8*)(bb + 1536);
            const int kk = (koff + ks) & 15;
            s16x8 a0 = *(const s16x8*)(ap0 + kk * 32);
            s16x8 a1 = *(const s16x8*)(ap1 + kk * 32);
            wait_lgkm0();             // slot reads landed before re-issue
            if (ks < 14) issue4(w2b, (koff + ks + 2) & 15, sb);
            acc[0][0] = MFMA16(a0, b0v, acc[0][0]);
            acc[1][0] = MFMA16(a1, b0v, acc[1][0]);
            acc[0][1] = MFMA16(a0, b1v, acc[0][1]);
            acc[1][1] = MFMA16(a1, b1v, acc[1][1]);
            acc[0][2] = MFMA16(a0, b2v, acc[0][2]);
            acc[1][2] = MFMA16(a1, b2v, acc[1][2]);
            acc[0][3] = MFMA16(a0, b3v, acc[0][3]);
            acc[1][3] = MFMA16(a1, b3v, acc[1][3]);
        }
    }

    // ---- W3 register preload (phase-3 B operands; BEFORE Ef prologue so
    //      phase-4 vmcnt counting sees only Ef chunks after each chunk) ----
    const int rowt = w >> 2;
    const int ot   = w & 3;
    const u16* bp3 = W3f + ot * 8192 + lane * 8;
    s16x8 W3pre[16];
#pragma unroll
    for (int k = 0; k < 16; ++k)
        W3pre[k] = *(const s16x8*)(bp3 + ((koff + k) & 15) * 512);

    // ---- Ef DMA prologue (slots 0,1) ----
    issue4(efb, (koff + 0) & 15, st0);
    issue4(efb, (koff + 1) & 15, st1);

    // all waves done READING h1 before overwriting with h2
    __syncthreads();

    // ---- phase-2 epilogue: tanh -> h2 (into h12s), d2 -> d2s ----
#pragma unroll
    for (int rt = 0; rt < 2; ++rt)
#pragma unroll
        for (int ct = 0; ct < 4; ++ct) {
            const int col = (4 * w + ct) * 16 + m16;
            const float bc = b2s[col];
#pragma unroll
            for (int i = 0; i < 4; ++i) {
                int row = rt * 16 + 4 * q + i;
                float hv = fast_tanh(acc[rt][ct][i] + bc);
                h12s[row * LP + col] = f2bf(hv);
                d2s[row * LP + col] = f2bf(1.0f - hv * hv);
            }
        }
    __syncthreads();

    // ---- phase 4: M = d2@Ef (DMA-staged); div = sum d1 .* M ----
    {
        f32x4 g[2][4];
#pragma unroll
        for (int rt = 0; rt < 2; ++rt)
#pragma unroll
            for (int ct = 0; ct < 4; ++ct) g[rt][ct] = (f32x4){0.f,0.f,0.f,0.f};
        const u16* dp0 = d2s + m16 * LP + kq;
        const u16* dp1 = d2s + (16 + m16) * LP + kq;
#pragma unroll
        for (int ks = 0; ks < 16; ++ks) {
            if (ks < 15) wait_vmcnt<4>(); else wait_vmcnt<0>();
            u16* sb = (ks & 1) ? st1 : st0;
            const u16* bb = sb + lane * 8;
            s16x8 e0 = *(const s16x8*)(bb);
            s16x8 e1 = *(const s16x8*)(bb + 512);
            s16x8 e2 = *(const s16x8*)(bb + 1024);
            s16x8 e3 = *(const s16x8*)(bb + 1536);
            const int kk = (koff + ks) & 15;
            s16x8 a0 = *(const s16x8*)(dp0 + kk * 32);
            s16x8 a1 = *(const s16x8*)(dp1 + kk * 32);
            wait_lgkm0();
            if (ks < 14) issue4(efb, (koff + ks + 2) & 15, sb);
            g[0][0] = MFMA16(a0, e0, g[0][0]);
            g[1][0] = MFMA16(a1, e0, g[1][0]);
            g[0][1] = MFMA16(a0, e1, g[0][1]);
            g[1][1] = MFMA16(a1, e1, g[1][1]);
            g[0][2] = MFMA16(a0, e2, g[0][2]);
            g[1][2] = MFMA16(a1, e2, g[1][2]);
            g[0][3] = MFMA16(a0, e3, g[0][3]);
            g[1][3] = MFMA16(a1, e3, g[1][3]);
        }
#pragma unroll
        for (int rt = 0; rt < 2; ++rt)
#pragma unroll
            for (int i = 0; i < 4; ++i) {
                float v = d1reg[rt][0][i] * g[rt][0][i]
                        + d1reg[rt][1][i] * g[rt][1][i]
                        + d1reg[rt][2][i] * g[rt][2][i]
                        + d1reg[rt][3][i] * g[rt][3][i];
                v += __shfl_xor(v, 1, 64);
                v += __shfl_xor(v, 2, 64);
                v += __shfl_xor(v, 4, 64);
                v += __shfl_xor(v, 8, 64);
                if (m16 == 0) divacc[w][rt * 16 + 4 * q + i] = v;
            }
    }

    // ---- phase 3 (one 16x16 tile per wave): dx = h2@W3 + b3 ----
    {
        const u16* ap3 = h12s + (rowt * 16 + m16) * LP + kq;
        f32x4 cA = {0.f,0.f,0.f,0.f}, cB = {0.f,0.f,0.f,0.f};
#pragma unroll
        for (int ks = 0; ks < 16; ++ks) {
            s16x8 f = *(const s16x8*)(ap3 + ((koff + ks) & 15) * 32);
            if (ks & 1) cB = MFMA16(f, W3pre[ks], cB);
            else        cA = MFMA16(f, W3pre[ks], cA);
        }
        f32x4 c3 = cA + cB;
        const int o = ot * 16 + m16;
#pragma unroll
        for (int i = 0; i < 4; ++i)
            out[(r0 + rowt * 16 + 4 * q + i) * (DD + 1) + o] = c3[i] + b3s[o];
    }
    __syncthreads();

    if (tid < MROWS) {
        float s = 0.0f;
#pragma unroll
        for (int ww = 0; ww < 8; ++ww) s += divacc[ww][tid];
        out[(r0 + tid) * (DD + 1) + DD] = s;
    }
}

extern "C" void kernel_launch(void* const* d_in, const int* in_sizes, int n_in,
                              void* d_out, int out_size, void* d_ws, size_t ws_size,
                              hipStream_t stream) {
    const float* t  = (const float*)d_in[0];
    const float* x  = (const float*)d_in[1];
    const float* W1 = (const float*)d_in[2];
    const float* b1 = (const float*)d_in[3];
    const float* W2 = (const float*)d_in[4];
    const float* b2 = (const float*)d_in[5];
    const float* W3 = (const float*)d_in[6];
    const float* b3 = (const float*)d_in[7];
    float* out = (float*)d_out;

    u16*   ws16 = (u16*)d_ws;
    float* z0   = (float*)((char*)d_ws + OFF_Z0B);

    precompute<<<137, 256, 0, stream>>>(t, W1, b1, W2, W3, ws16, z0);
    cnf_main<<<8192 / MROWS, TPB, 0, stream>>>(x, ws16, z0, b2, b3, out);
}